// Round 13
// baseline (561.075 us; speedup 1.0000x reference)
//
#include <hip/hip_runtime.h>
#include <cstdint>
#include <cstddef>

typedef __bf16 bf16_t;
typedef __attribute__((ext_vector_type(8))) __bf16 bf16x8;
typedef __attribute__((ext_vector_type(4))) __bf16 bf16x4;
typedef __attribute__((ext_vector_type(4))) float f32x4;

constexpr int D  = 1024;   // d_model
constexpr int TT = 1024;   // seq len
constexpr int BB = 4;      // batch
constexpr int NH = 16;     // heads
constexpr int HS = 64;     // head size
constexpr int MR = BB * TT; // 4096 rows
constexpr int HF = 4096;   // ffn hidden

__device__ inline void gload_lds16(const bf16_t* g, bf16_t* l)
{
    __builtin_amdgcn_global_load_lds(
        (const __attribute__((address_space(1))) void*)g,
        (__attribute__((address_space(3))) void*)l, 16, 0, 0);
}

// ---------------------------------------------------------------------------
// RMSNorm: f32 in -> bf16 hi (+ optional lo) planes. One block per row.
// ---------------------------------------------------------------------------
template<bool LO>
__global__ __launch_bounds__(256) void rmsnorm_kernel(const float* __restrict__ x,
                                                      const float* __restrict__ gamma,
                                                      bf16_t* __restrict__ oh,
                                                      bf16_t* __restrict__ ol)
{
    int row = blockIdx.x;
    int t   = threadIdx.x;
    const float* xr = x + (size_t)row * D;
    float4 xv = *(const float4*)(xr + t * 4);
    float ss = xv.x * xv.x + xv.y * xv.y + xv.z * xv.z + xv.w * xv.w;
#pragma unroll
    for (int m = 1; m < 64; m <<= 1) ss += __shfl_xor(ss, m, 64);
    __shared__ float part[4];
    if ((t & 63) == 0) part[t >> 6] = ss;
    __syncthreads();
    float tot   = part[0] + part[1] + part[2] + part[3];
    float scale = rsqrtf(tot * (1.0f / D) + 1e-6f);
    float4 gv = *(const float4*)(gamma + t * 4);
    float vals[4] = {xv.x * scale * gv.x, xv.y * scale * gv.y,
                     xv.z * scale * gv.z, xv.w * scale * gv.w};
    bf16x4 vh, vl;
#pragma unroll
    for (int j = 0; j < 4; ++j) {
        bf16_t h = (bf16_t)vals[j];
        vh[j] = h;
        vl[j] = (bf16_t)(vals[j] - (float)h);
    }
    *(bf16x4*)(oh + (size_t)row * D + t * 4) = vh;
    if (LO) *(bf16x4*)(ol + (size_t)row * D + t * 4) = vl;
}

// ---------------------------------------------------------------------------
// concat 3x [1024] f32 biases into one [3072] buffer
// ---------------------------------------------------------------------------
__global__ __launch_bounds__(256) void concat_bias_kernel(const float* __restrict__ a,
                                                          const float* __restrict__ b,
                                                          const float* __restrict__ c,
                                                          float* __restrict__ o)
{
    int i = blockIdx.x * 256 + threadIdx.x;
    o[i] = i < 1024 ? a[i] : (i < 2048 ? b[i - 1024] : c[i - 2048]);
}

// ---------------------------------------------------------------------------
// Weight convert: W f32 [K][N] -> dH (+ optional dL) bf16 [N][K] (transposed).
// 64x64 tile via padded LDS transpose. Grid (K/64, N/64), 256 thr.
// ---------------------------------------------------------------------------
template<bool LO>
__global__ __launch_bounds__(256) void convw_kernel(const float* __restrict__ W,
                                                    bf16_t* __restrict__ dH,
                                                    bf16_t* __restrict__ dL,
                                                    int K, int N)
{
    __shared__ float sld[64][65];
    int t = threadIdx.x;
    int k0 = blockIdx.x * 64, n0 = blockIdx.y * 64;
    int kr = t >> 4, nc = (t & 15) * 4;
#pragma unroll
    for (int p = 0; p < 4; ++p) {
        int k = p * 16 + kr;
        float4 v = *(const float4*)(W + (size_t)(k0 + k) * N + n0 + nc);
        sld[k][nc] = v.x; sld[k][nc + 1] = v.y; sld[k][nc + 2] = v.z; sld[k][nc + 3] = v.w;
    }
    __syncthreads();
    int n = t >> 2, kh = (t & 3) * 16;
    bf16x8 h0, l0, h1, l1;
#pragma unroll
    for (int j = 0; j < 8; ++j) {
        float v = sld[kh + j][n];
        bf16_t h = (bf16_t)v;
        h0[j] = h; l0[j] = (bf16_t)(v - (float)h);
    }
#pragma unroll
    for (int j = 0; j < 8; ++j) {
        float v = sld[kh + 8 + j][n];
        bf16_t h = (bf16_t)v;
        h1[j] = h; l1[j] = (bf16_t)(v - (float)h);
    }
    size_t o = (size_t)(n0 + n) * K + k0 + kh;
    *(bf16x8*)(dH + o)     = h0;
    *(bf16x8*)(dH + o + 8) = h1;
    if (LO) {
        *(bf16x8*)(dL + o)     = l0;
        *(bf16x8*)(dL + o + 8) = l1;
    }
}

// ---------------------------------------------------------------------------
// Split-precision GEMM, 128xTN tile (TN = 64 or 128), BK=32, 4 waves.
// A bf16 [M][K] hi (+ lo if ALO); W bf16 [N][K] hi (+ lo if WLO).
// MFMA passes: hh, + hl (if WLO), + lh (if ALO).
// global_load_lds(16B) staging into linear LDS, XOR-swizzled source+read.
// OUTM: 0 = f32 out, 1 = bf16 hi/lo planes, 2 = bf16 hi only,
//       3 = bf16 hi always + lo only for cols < 2048 (QKV: V-lo is dead).
// ---------------------------------------------------------------------------
template<int TN, bool ALO, bool WLO, int OUTM, bool RELU, bool RESID>
__global__ __launch_bounds__(256, 2) void gemm_kernel(
    const bf16_t* __restrict__ Ahp, const bf16_t* __restrict__ Alp,
    const bf16_t* __restrict__ Whp, const bf16_t* __restrict__ Wlp,
    const float* __restrict__ bias, const float* resid,
    float* outf, bf16_t* __restrict__ outh, bf16_t* __restrict__ outl,
    int N, int K)
{
    constexpr int NF = TN / 32;          // n-frags per wave
    constexpr int AP = ALO ? 2 : 1;      // A planes
    constexpr int WP = WLO ? 2 : 1;      // W planes
    __shared__ bf16_t sA[AP][128][32];   // [plane][m][k], linear (gload_lds dest)
    __shared__ bf16_t sW[WP][TN][32];    // [plane][n][k]

    int t = threadIdx.x;
    int l = t & 63, w = t >> 6;
    int lr = l & 15, lg = l >> 4;

    // XCD-aware block swizzle (all grids have nwg % 8 == 0)
    int gx  = gridDim.x;
    int nwg = gx * gridDim.y;
    int bid = blockIdx.y * gx + blockIdx.x;
    int s   = (bid & 7) * (nwg >> 3) + (bid >> 3);
    int nb  = s % gx, mb = s / gx;
    int m0 = mb * 128, n0 = nb * TN;
    int wr = (w >> 1) * 64, wc = (w & 1) * (TN / 2);

    f32x4 acc[4][NF] = {};

    int srow = (l >> 2);      // 0..15 within chunk
    int sch  = l & 3;         // 16B slot within 64B row

    for (int kk = 0; kk < K; kk += 32) {
        __syncthreads();
        // A planes: 128 rows = 4 waves x 2 chunks x 16
#pragma unroll
        for (int c = 0; c < 2; ++c) {
            int rbase = w * 32 + c * 16;
            int row = rbase + srow;
            int f = (row >> 1) & 3;
            size_t goff = (size_t)row * K + kk + (size_t)((sch ^ f)) * 8;
            gload_lds16(Ahp + (size_t)m0 * K + goff, &sA[0][rbase][0]);
            if (ALO) gload_lds16(Alp + (size_t)m0 * K + goff, &sA[AP - 1][rbase][0]);
        }
        // W planes: TN rows = 4 waves x (TN/64) chunks x 16
#pragma unroll
        for (int c = 0; c < TN / 64; ++c) {
            int rbase = w * (TN / 4) + c * 16;
            int row = rbase + srow;
            int f = (row >> 1) & 3;
            size_t goff = (size_t)row * K + kk + (size_t)((sch ^ f)) * 8;
            gload_lds16(Whp + (size_t)n0 * K + goff, &sW[0][rbase][0]);
            if (WLO) gload_lds16(Wlp + (size_t)n0 * K + goff, &sW[WP - 1][rbase][0]);
        }
        __syncthreads();

        bf16x8 a0[4], a1[4], b0[NF], b1[NF];
#pragma unroll
        for (int m = 0; m < 4; ++m) {
            int row = wr + m * 16 + lr;
            int sl = lg ^ ((row >> 1) & 3);
            a0[m] = *(const bf16x8*)&sA[0][row][sl * 8];
            if (ALO) a1[m] = *(const bf16x8*)&sA[AP - 1][row][sl * 8];
        }
#pragma unroll
        for (int n = 0; n < NF; ++n) {
            int row = wc + n * 16 + lr;
            int sl = lg ^ ((row >> 1) & 3);
            b0[n] = *(const bf16x8*)&sW[0][row][sl * 8];
            if (WLO) b1[n] = *(const bf16x8*)&sW[WP - 1][row][sl * 8];
        }
        // hh pass, then (if WLO) hl, then (if ALO) lh
#pragma unroll
        for (int m = 0; m < 4; ++m)
#pragma unroll
            for (int n = 0; n < NF; ++n)
                acc[m][n] = __builtin_amdgcn_mfma_f32_16x16x32_bf16(a0[m], b0[n], acc[m][n], 0, 0, 0);
        if (WLO) {
#pragma unroll
            for (int m = 0; m < 4; ++m)
#pragma unroll
                for (int n = 0; n < NF; ++n)
                    acc[m][n] = __builtin_amdgcn_mfma_f32_16x16x32_bf16(a0[m], b1[n], acc[m][n], 0, 0, 0);
        }
        if (ALO) {
#pragma unroll
            for (int m = 0; m < 4; ++m)
#pragma unroll
                for (int n = 0; n < NF; ++n)
                    acc[m][n] = __builtin_amdgcn_mfma_f32_16x16x32_bf16(a1[m], b0[n], acc[m][n], 0, 0, 0);
        }
    }

#pragma unroll
    for (int m = 0; m < 4; ++m) {
#pragma unroll
        for (int n = 0; n < NF; ++n) {
            int col = n0 + wc + n * 16 + lr;
            float bv = bias[col];
#pragma unroll
            for (int r = 0; r < 4; ++r) {
                int row = m0 + wr + m * 16 + lg * 4 + r;
                float v = acc[m][n][r] + bv;
                if (RELU)  v = (v >= 0.0f) ? v : 0.1f * v;
                if (RESID) v += resid[(size_t)row * N + col];
                if (OUTM == 0) {
                    outf[(size_t)row * N + col] = v;
                } else if (OUTM == 2) {
                    outh[(size_t)row * N + col] = (bf16_t)v;
                } else {
                    bf16_t h = (bf16_t)v;
                    outh[(size_t)row * N + col] = h;
                    if (OUTM == 1 || col < 2048)
                        outl[(size_t)row * N + col] = (bf16_t)(v - (float)h);
                }
            }
        }
    }
}

// ---------------------------------------------------------------------------
// Flash attention from fused QKV planes (row stride 3D; q/k/v at col 0/D/2D).
// Block = 128 thr (2 waves), 64 q-rows per block (32/wave): keeps per-wave
// K-load amortization (r8 lesson), but doubles grid to 1024 blocks ->
// ~6 blocks/CU (LDS 24.8KB) in independent barrier domains, so waves from
// other blocks cover each block's per-tile barrier stall (r12 fix; r11's
// 512-block grid = 2 gang-barriered blocks/CU left 57% of cycles idle).
// XCD locality: h = blockIdx.x in both variants -> all q-blocks of a head
// on ONE XCD; K/V L2-resident (r11: FETCH 106->20 MB).
// Causal balance: co-CU blocks differ only in z (ids +-256), so
// qb = (z&1) ? 15-y : y gives every CU a uniform 34 tiles.
// Pipelining: K(t+1) frags prefetched into regs after QK^T(t); V double-
// buffered in LDS with single barrier per tile (validated r8-r11).
// QK^T split-precision (3 MFMA/pair); PV pure bf16-hi. O stored hi-only.
// ---------------------------------------------------------------------------
template<bool CAUSAL>
__global__ __launch_bounds__(128, 2) void attn_kernel(
    const bf16_t* __restrict__ qkvH, const bf16_t* __restrict__ qkvL,
    bf16_t* __restrict__ oh)
{
    __shared__ bf16_t Vth[2][64][66];  // double-buffered V^T (hi), pad 66
    __shared__ bf16_t Ph[2][32][66];   // per-wave P tile (hi)

    int tid = threadIdx.x;
    int b = blockIdx.z;
    int qb, h;
    if (CAUSAL) {
        qb = (blockIdx.z & 1) ? (15 - blockIdx.y) : blockIdx.y;
        h  = blockIdx.x;
    } else {
        h  = blockIdx.x;       // grid (NH, 16, BB): head pinned to XCD
        qb = blockIdx.y;
    }
    int l = tid & 63, w = tid >> 6;    // 2 waves
    int lr = l & 15, lg = l >> 4;
    int qbase = qb * 64;
    const int QS = 3 * D;

    // Q frags: 32 rows per wave (2 x 16-row frags), hi/lo, both k-halves
    bf16x8 aqh[2][2], aql[2][2];
#pragma unroll
    for (int m = 0; m < 2; ++m) {
        size_t qoff = (size_t)(b * TT + qbase + w * 32 + m * 16 + lr) * QS + h * HS;
#pragma unroll
        for (int c = 0; c < 2; ++c) {
            aqh[m][c] = *(const bf16x8*)(qkvH + qoff + c * 32 + lg * 8);
            aql[m][c] = *(const bf16x8*)(qkvL + qoff + c * 32 + lg * 8);
        }
    }

    float mrow[2][4], lsum[2][4];
    f32x4 acc_o[2][4] = {};
#pragma unroll
    for (int m = 0; m < 2; ++m)
#pragma unroll
        for (int r = 0; r < 4; ++r) { mrow[m][r] = -1e30f; lsum[m][r] = 0.0f; }

    int ktmax = CAUSAL ? qb : (TT / 64 - 1);

    int vrow = tid >> 3;          // 0..15 (4 rows per thread, +16 apart)
    int vcol = (tid & 7) * 8;

    // prologue: V(0) -> LDS buf0; K(0) -> regs
    bf16x8 vreg[4];
#pragma unroll
    for (int rr = 0; rr < 4; ++rr)
        vreg[rr] = *(const bf16x8*)(qkvH + (size_t)(b * TT + vrow + rr * 16) * QS + 2 * D + h * HS + vcol);
#pragma unroll
    for (int rr = 0; rr < 4; ++rr)
#pragma unroll
        for (int j = 0; j < 8; ++j) Vth[0][vcol + j][vrow + rr * 16] = vreg[rr][j];

    bf16x8 kh0[4], kl0[4], kh1[4], kl1[4];
    {
        size_t koff = (size_t)(b * TT + lr) * QS + D + h * HS;
#pragma unroll
        for (int nt = 0; nt < 4; ++nt) {
            size_t ko = koff + (size_t)(nt * 16) * QS;
            kh0[nt] = *(const bf16x8*)(qkvH + ko + lg * 8);
            kl0[nt] = *(const bf16x8*)(qkvL + ko + lg * 8);
            kh1[nt] = *(const bf16x8*)(qkvH + ko + 32 + lg * 8);
            kl1[nt] = *(const bf16x8*)(qkvL + ko + 32 + lg * 8);
        }
    }
    __syncthreads();
    int cur = 0;

    for (int kt = 0; kt <= ktmax; ++kt) {
        int kbase = kt * 64;
        int ktn = kt < ktmax ? kt + 1 : ktmax;

        // issue V(t+1) loads (hide under QK^T + softmax + PV)
#pragma unroll
        for (int rr = 0; rr < 4; ++rr)
            vreg[rr] = *(const bf16x8*)(qkvH + (size_t)(b * TT + ktn * 64 + vrow + rr * 16) * QS + 2 * D + h * HS + vcol);

        // S = Q K^T  (32 q-rows x 64 k-cols per wave), split 3-MFMA, K from regs
        f32x4 accs[2][4];
#pragma unroll
        for (int nt = 0; nt < 4; ++nt) {
            __builtin_amdgcn_s_setprio(1);
#pragma unroll
            for (int m = 0; m < 2; ++m) {
                f32x4 s = {};
                s = __builtin_amdgcn_mfma_f32_16x16x32_bf16(aqh[m][0], kh0[nt], s, 0, 0, 0);
                s = __builtin_amdgcn_mfma_f32_16x16x32_bf16(aqh[m][0], kl0[nt], s, 0, 0, 0);
                s = __builtin_amdgcn_mfma_f32_16x16x32_bf16(aql[m][0], kh0[nt], s, 0, 0, 0);
                s = __builtin_amdgcn_mfma_f32_16x16x32_bf16(aqh[m][1], kh1[nt], s, 0, 0, 0);
                s = __builtin_amdgcn_mfma_f32_16x16x32_bf16(aqh[m][1], kl1[nt], s, 0, 0, 0);
                s = __builtin_amdgcn_mfma_f32_16x16x32_bf16(aql[m][1], kh1[nt], s, 0, 0, 0);
                accs[m][nt] = s * 8.0f;   // * sqrt(head_size), faithful to reference
            }
            __builtin_amdgcn_s_setprio(0);
        }

        // prefetch K(t+1) fragments (old K regs dead; softmax+PV hide latency)
        {
            size_t koffn = (size_t)(b * TT + ktn * 64 + lr) * QS + D + h * HS;
#pragma unroll
            for (int nt = 0; nt < 4; ++nt) {
                size_t ko = koffn + (size_t)(nt * 16) * QS;
                kh0[nt] = *(const bf16x8*)(qkvH + ko + lg * 8);
                kl0[nt] = *(const bf16x8*)(qkvL + ko + lg * 8);
                kh1[nt] = *(const bf16x8*)(qkvH + ko + 32 + lg * 8);
                kl1[nt] = *(const bf16x8*)(qkvL + ko + 32 + lg * 8);
            }
        }

        if (CAUSAL && kt >= qb) {
#pragma unroll
            for (int m = 0; m < 2; ++m)
#pragma unroll
                for (int nt = 0; nt < 4; ++nt)
#pragma unroll
                    for (int r = 0; r < 4; ++r) {
                        int qrow = qbase + w * 32 + m * 16 + lg * 4 + r;
                        int kcol = kbase + nt * 16 + lr;
                        if (kcol > qrow) accs[m][nt][r] = -1e30f;
                    }
        }

        // online softmax (row-wise over the 16 lanes holding this row)
#pragma unroll
        for (int m = 0; m < 2; ++m) {
            float alpha[4];
#pragma unroll
            for (int r = 0; r < 4; ++r) {
                float mx = fmaxf(fmaxf(accs[m][0][r], accs[m][1][r]),
                                 fmaxf(accs[m][2][r], accs[m][3][r]));
#pragma unroll
                for (int msk = 1; msk < 16; msk <<= 1) mx = fmaxf(mx, __shfl_xor(mx, msk, 64));
                float mnew = fmaxf(mrow[m][r], mx);
                float sum = 0.0f;
#pragma unroll
                for (int nt = 0; nt < 4; ++nt) {
                    float p = __expf(accs[m][nt][r] - mnew);
                    accs[m][nt][r] = p;
                    sum += p;
                }
#pragma unroll
                for (int msk = 1; msk < 16; msk <<= 1) sum += __shfl_xor(sum, msk, 64);
                alpha[r] = __expf(mrow[m][r] - mnew);
                lsum[m][r] = lsum[m][r] * alpha[r] + sum;
                mrow[m][r] = mnew;
            }
#pragma unroll
            for (int et = 0; et < 4; ++et)
#pragma unroll
                for (int r = 0; r < 4; ++r) acc_o[m][et][r] *= alpha[r];

            // P -> LDS (bf16 hi only; wave-private, no barrier needed)
#pragma unroll
            for (int nt = 0; nt < 4; ++nt)
#pragma unroll
                for (int r = 0; r < 4; ++r)
                    Ph[w][m * 16 + lg * 4 + r][nt * 16 + lr] = (bf16_t)accs[m][nt][r];
        }

        // O += P @ V  (pure bf16) from current V buffer
#pragma unroll
        for (int m = 0; m < 2; ++m) {
            bf16x8 ap0 = *(const bf16x8*)&Ph[w][m * 16 + lr][lg * 8];
            bf16x8 ap1 = *(const bf16x8*)&Ph[w][m * 16 + lr][32 + lg * 8];
            __builtin_amdgcn_s_setprio(1);
#pragma unroll
            for (int et = 0; et < 4; ++et) {
                bf16x8 bv0 = *(const bf16x8*)&Vth[cur][et * 16 + lr][lg * 8];
                bf16x8 bv1 = *(const bf16x8*)&Vth[cur][et * 16 + lr][32 + lg * 8];
                acc_o[m][et] = __builtin_amdgcn_mfma_f32_16x16x32_bf16(ap0, bv0, acc_o[m][et], 0, 0, 0);
                acc_o[m][et] = __builtin_amdgcn_mfma_f32_16x16x32_bf16(ap1, bv1, acc_o[m][et], 0, 0, 0);
            }
            __builtin_amdgcn_s_setprio(0);
        }

        // stage V(t+1) into the other buffer, then the single barrier
#pragma unroll
        for (int rr = 0; rr < 4; ++rr)
#pragma unroll
            for (int j = 0; j < 8; ++j) Vth[cur ^ 1][vcol + j][vrow + rr * 16] = vreg[rr][j];
        __syncthreads();
        cur ^= 1;
    }

#pragma unroll
    for (int m = 0; m < 2; ++m) {
        size_t obase = (size_t)(b * TT + qbase + w * 32 + m * 16) * D + h * HS;
#pragma unroll
        for (int r = 0; r < 4; ++r) {
            float inv = 1.0f / lsum[m][r];
#pragma unroll
            for (int et = 0; et < 4; ++et) {
                float v = acc_o[m][et][r] * inv;
                size_t idx = obase + (size_t)(lg * 4 + r) * D + et * 16 + lr;
                oh[idx] = (bf16_t)v;
            }
        }
    }
}

// ---------------------------------------------------------------------------
extern "C" void kernel_launch(void* const* d_in, const int* in_sizes, int n_in,
                              void* d_out, int out_size, void* d_ws, size_t ws_size,
                              hipStream_t stream)
{
    const float* x     = (const float*)d_in[0];
    const float* Wq    = (const float*)d_in[1];
    const float* bq    = (const float*)d_in[2];
    const float* Wk    = (const float*)d_in[3];
    const float* bk    = (const float*)d_in[4];
    const float* Wv    = (const float*)d_in[5];
    const float* bv    = (const float*)d_in[6];
    const float* Wp    = (const float*)d_in[7];
    const float* bp    = (const float*)d_in[8];
    const float* gamma = (const float*)d_in[9];
    const float* W1    = (const float*)d_in[10];
    const float* b1    = (const float*)d_in[11];
    const float* W2    = (const float*)d_in[12];
    const float* b2    = (const float*)d_in[13];
    float* out = (float*)d_out;

    // workspace layout (96 MB):
    //  0..16  : nrm hi/lo (8 MB each); ao hi (aliased)
    // 16..64  : qkv hi (24) + qkv lo (24); h1 bf16-hi (32) aliases 16..48
    // 48..64  : W1 conv slot (16 MB, ffn phase; aliases qkv lo tail)
    // 64..80  : bias3072 (attn phases) / W2 conv slot (8 MB used, ffn phase)
    // 80..96  : persistent attn weights: wqkv hi 6, wqkv lo 6, wp hi 2, wp lo 2
    char* base = (char*)d_ws;
    bf16_t* nrmH  = (bf16_t*)(base);
    bf16_t* nrmL  = (bf16_t*)(base + (8u  << 20));
    bf16_t* qkvH  = (bf16_t*)(base + (16u << 20));
    bf16_t* qkvL  = (bf16_t*)(base + (40u << 20));
    bf16_t* h1H   = (bf16_t*)(base + (16u << 20));   // 32 MB, hi only
    bf16_t* w1sl  = (bf16_t*)(base + (48u << 20));   // 16 MB (hi+lo)
    float*  bias3 = (float*)(base + (64u << 20));
    bf16_t* w2sl  = (bf16_t*)(base + (64u << 20));   // 8 MB (hi only)
    bf16_t* wsl   = (bf16_t*)(base + (80u << 20));   // 16 MB persistent
    bf16_t* aoH = nrmH;
    float* abuf = out;   // 'a' lives in d_out, dead before final write
    float* bbuf = out;   // 'b' overwrites 'a' in d_out (a unused after rmsnorm)

    // persistent attn weights: wqkv hi [3072][1024], wqkv lo, wp hi, wp lo
    size_t DD = (size_t)D * D;
    bf16_t* wqkvH = wsl;
    bf16_t* wqkvL = wsl + 3 * DD;
    bf16_t* wpH   = wsl + 6 * DD;
    bf16_t* wpL   = wsl + 7 * DD;

    dim3 blk(256);
    dim3 blkA(128);
    dim3 gcvD(D / 64, D / 64);
    dim3 gcv1(D / 64, HF / 64);
    dim3 gcv2(HF / 64, D / 64);
    dim3 gQKV(3 * D / 128, MR / 128);   // 24 x 32 = 768 blocks, TN=128
    dim3 gP(D / 64, MR / 128);          // 16 x 32 = 512 blocks, TN=64
    dim3 gF(HF / 128, MR / 128);        // 32 x 32 = 1024 blocks, TN=128
    dim3 gA(NH, TT / 64, BB);           // 16 x 16 x 4 = 1024 blocks, 128 thr

    // ---- a = x + attn(rmsnorm(x), causal=false)
    rmsnorm_kernel<true><<<MR, blk, 0, stream>>>(x, gamma, nrmH, nrmL);
    concat_bias_kernel<<<12, blk, 0, stream>>>(bq, bk, bv, bias3);
    convw_kernel<true><<<gcvD, blk, 0, stream>>>(Wq, wqkvH,          wqkvL,          D, D);
    convw_kernel<true><<<gcvD, blk, 0, stream>>>(Wk, wqkvH + DD,     wqkvL + DD,     D, D);
    convw_kernel<true><<<gcvD, blk, 0, stream>>>(Wv, wqkvH + 2 * DD, wqkvL + 2 * DD, D, D);
    convw_kernel<true><<<gcvD, blk, 0, stream>>>(Wp, wpH,            wpL,            D, D);
    gemm_kernel<128, true, true, 3, false, false><<<gQKV, blk, 0, stream>>>(nrmH, nrmL, wqkvH, wqkvL, bias3, nullptr, nullptr, qkvH, qkvL, 3 * D, D);
    attn_kernel<false><<<gA, blkA, 0, stream>>>(qkvH, qkvL, aoH);
    gemm_kernel<64, false, true, 0, false, true><<<gP, blk, 0, stream>>>(aoH, nullptr, wpH, wpL, bp, x, abuf, nullptr, nullptr, D, D);

    // ---- b = x + ffwd(rmsnorm(a))
    rmsnorm_kernel<false><<<MR, blk, 0, stream>>>(abuf, gamma, nrmH, nullptr);
    convw_kernel<true><<<gcv1, blk, 0, stream>>>(W1, w1sl, w1sl + (size_t)HF * D, D, HF);
    gemm_kernel<128, false, true, 2, true, false><<<gF, blk, 0, stream>>>(nrmH, nullptr, w1sl, w1sl + (size_t)HF * D, b1, nullptr, nullptr, h1H, nullptr, HF, D);
    convw_kernel<false><<<gcv2, blk, 0, stream>>>(W2, w2sl, nullptr, HF, D);
    gemm_kernel<64, false, false, 0, false, true><<<gP, blk, 0, stream>>>(h1H, nullptr, w2sl, nullptr, b2, x, bbuf, nullptr, nullptr, D, HF);

    // ---- c = b + attn(rmsnorm(b), causal=true)  (attn weights still resident)
    rmsnorm_kernel<true><<<MR, blk, 0, stream>>>(bbuf, gamma, nrmH, nrmL);
    concat_bias_kernel<<<12, blk, 0, stream>>>(bq, bk, bv, bias3);
    gemm_kernel<128, true, true, 3, false, false><<<gQKV, blk, 0, stream>>>(nrmH, nrmL, wqkvH, wqkvL, bias3, nullptr, nullptr, qkvH, qkvL, 3 * D, D);
    attn_kernel<true><<<gA, blkA, 0, stream>>>(qkvH, qkvL, aoH);
    gemm_kernel<64, false, true, 0, false, true><<<gP, blk, 0, stream>>>(aoH, nullptr, wpH, wpL, bp, bbuf, out, nullptr, nullptr, D, D);
}

// Round 14
// 553.358 us; speedup vs baseline: 1.0139x; 1.0139x over previous
//
#include <hip/hip_runtime.h>
#include <cstdint>
#include <cstddef>

typedef __bf16 bf16_t;
typedef __attribute__((ext_vector_type(8))) __bf16 bf16x8;
typedef __attribute__((ext_vector_type(4))) __bf16 bf16x4;
typedef __attribute__((ext_vector_type(4))) float f32x4;

constexpr int D  = 1024;   // d_model
constexpr int TT = 1024;   // seq len
constexpr int BB = 4;      // batch
constexpr int NH = 16;     // heads
constexpr int HS = 64;     // head size
constexpr int MR = BB * TT; // 4096 rows
constexpr int HF = 4096;   // ffn hidden

__device__ inline void gload_lds16(const bf16_t* g, bf16_t* l)
{
    __builtin_amdgcn_global_load_lds(
        (const __attribute__((address_space(1))) void*)g,
        (__attribute__((address_space(3))) void*)l, 16, 0, 0);
}

// ---------------------------------------------------------------------------
// RMSNorm: f32 in -> bf16 hi (+ optional lo) planes. One block per row.
// ---------------------------------------------------------------------------
template<bool LO>
__global__ __launch_bounds__(256) void rmsnorm_kernel(const float* __restrict__ x,
                                                      const float* __restrict__ gamma,
                                                      bf16_t* __restrict__ oh,
                                                      bf16_t* __restrict__ ol)
{
    int row = blockIdx.x;
    int t   = threadIdx.x;
    const float* xr = x + (size_t)row * D;
    float4 xv = *(const float4*)(xr + t * 4);
    float ss = xv.x * xv.x + xv.y * xv.y + xv.z * xv.z + xv.w * xv.w;
#pragma unroll
    for (int m = 1; m < 64; m <<= 1) ss += __shfl_xor(ss, m, 64);
    __shared__ float part[4];
    if ((t & 63) == 0) part[t >> 6] = ss;
    __syncthreads();
    float tot   = part[0] + part[1] + part[2] + part[3];
    float scale = rsqrtf(tot * (1.0f / D) + 1e-6f);
    float4 gv = *(const float4*)(gamma + t * 4);
    float vals[4] = {xv.x * scale * gv.x, xv.y * scale * gv.y,
                     xv.z * scale * gv.z, xv.w * scale * gv.w};
    bf16x4 vh, vl;
#pragma unroll
    for (int j = 0; j < 4; ++j) {
        bf16_t h = (bf16_t)vals[j];
        vh[j] = h;
        vl[j] = (bf16_t)(vals[j] - (float)h);
    }
    *(bf16x4*)(oh + (size_t)row * D + t * 4) = vh;
    if (LO) *(bf16x4*)(ol + (size_t)row * D + t * 4) = vl;
}

// ---------------------------------------------------------------------------
// concat 3x [1024] f32 biases into one [3072] buffer
// ---------------------------------------------------------------------------
__global__ __launch_bounds__(256) void concat_bias_kernel(const float* __restrict__ a,
                                                          const float* __restrict__ b,
                                                          const float* __restrict__ c,
                                                          float* __restrict__ o)
{
    int i = blockIdx.x * 256 + threadIdx.x;
    o[i] = i < 1024 ? a[i] : (i < 2048 ? b[i - 1024] : c[i - 2048]);
}

// ---------------------------------------------------------------------------
// Weight convert: W f32 [K][N] -> dH (+ optional dL) bf16 [N][K] (transposed).
// 64x64 tile via padded LDS transpose. Grid (K/64, N/64), 256 thr.
// ---------------------------------------------------------------------------
template<bool LO>
__global__ __launch_bounds__(256) void convw_kernel(const float* __restrict__ W,
                                                    bf16_t* __restrict__ dH,
                                                    bf16_t* __restrict__ dL,
                                                    int K, int N)
{
    __shared__ float sld[64][65];
    int t = threadIdx.x;
    int k0 = blockIdx.x * 64, n0 = blockIdx.y * 64;
    int kr = t >> 4, nc = (t & 15) * 4;
#pragma unroll
    for (int p = 0; p < 4; ++p) {
        int k = p * 16 + kr;
        float4 v = *(const float4*)(W + (size_t)(k0 + k) * N + n0 + nc);
        sld[k][nc] = v.x; sld[k][nc + 1] = v.y; sld[k][nc + 2] = v.z; sld[k][nc + 3] = v.w;
    }
    __syncthreads();
    int n = t >> 2, kh = (t & 3) * 16;
    bf16x8 h0, l0, h1, l1;
#pragma unroll
    for (int j = 0; j < 8; ++j) {
        float v = sld[kh + j][n];
        bf16_t h = (bf16_t)v;
        h0[j] = h; l0[j] = (bf16_t)(v - (float)h);
    }
#pragma unroll
    for (int j = 0; j < 8; ++j) {
        float v = sld[kh + 8 + j][n];
        bf16_t h = (bf16_t)v;
        h1[j] = h; l1[j] = (bf16_t)(v - (float)h);
    }
    size_t o = (size_t)(n0 + n) * K + k0 + kh;
    *(bf16x8*)(dH + o)     = h0;
    *(bf16x8*)(dH + o + 8) = h1;
    if (LO) {
        *(bf16x8*)(dL + o)     = l0;
        *(bf16x8*)(dL + o + 8) = l1;
    }
}

// ---------------------------------------------------------------------------
// Split-precision GEMM, 128xTN tile (TN = 64 or 128), BK=32, 4 waves.
// A bf16 [M][K] hi (+ lo if ALO); W bf16 [N][K] hi (+ lo if WLO).
// MFMA passes: hh, + hl (if WLO), + lh (if ALO).
// global_load_lds(16B) staging into linear LDS, XOR-swizzled source+read.
// XCD swizzle: CM=false -> A-chunk resident per XCD (stream B; default,
// best when A total < B total). CM=true -> B-chunk resident per XCD
// (stream A; W1: A=8MB < B=16MB -> per-XCD 8+2MB = ~80MB total vs 164).
// OUTM: 0 = f32 out, 1 = bf16 hi/lo planes, 2 = bf16 hi only,
//       3 = bf16 hi always + lo only for cols < 2048 (QKV: V-lo is dead).
// ---------------------------------------------------------------------------
template<int TN, bool CM, bool ALO, bool WLO, int OUTM, bool RELU, bool RESID>
__global__ __launch_bounds__(256, 2) void gemm_kernel(
    const bf16_t* __restrict__ Ahp, const bf16_t* __restrict__ Alp,
    const bf16_t* __restrict__ Whp, const bf16_t* __restrict__ Wlp,
    const float* __restrict__ bias, const float* resid,
    float* outf, bf16_t* __restrict__ outh, bf16_t* __restrict__ outl,
    int N, int K)
{
    constexpr int NF = TN / 32;          // n-frags per wave
    constexpr int AP = ALO ? 2 : 1;      // A planes
    constexpr int WP = WLO ? 2 : 1;      // W planes
    __shared__ bf16_t sA[AP][128][32];   // [plane][m][k], linear (gload_lds dest)
    __shared__ bf16_t sW[WP][TN][32];    // [plane][n][k]

    int t = threadIdx.x;
    int l = t & 63, w = t >> 6;
    int lr = l & 15, lg = l >> 4;

    int gx  = gridDim.x;
    int gy  = gridDim.y;
    int nwg = gx * gy;
    int bid = blockIdx.y * gx + blockIdx.x;
    int xcd = bid & 7, idx = bid >> 3;
    int nb, mb;
    if (CM) {
        // B-chunk resident: XCD owns nb in [xcd*gx/8, (xcd+1)*gx/8), mb fast
        int cw = gx >> 3;
        mb = idx % gy;
        nb = xcd * cw + idx / gy;
    } else {
        // A-chunk resident: XCD owns contiguous s-range (nb fast)
        int s = xcd * (nwg >> 3) + idx;
        nb = s % gx; mb = s / gx;
    }
    int m0 = mb * 128, n0 = nb * TN;
    int wr = (w >> 1) * 64, wc = (w & 1) * (TN / 2);

    f32x4 acc[4][NF] = {};

    int srow = (l >> 2);      // 0..15 within chunk
    int sch  = l & 3;         // 16B slot within 64B row

    for (int kk = 0; kk < K; kk += 32) {
        __syncthreads();
        // A planes: 128 rows = 4 waves x 2 chunks x 16
#pragma unroll
        for (int c = 0; c < 2; ++c) {
            int rbase = w * 32 + c * 16;
            int row = rbase + srow;
            int f = (row >> 1) & 3;
            size_t goff = (size_t)row * K + kk + (size_t)((sch ^ f)) * 8;
            gload_lds16(Ahp + (size_t)m0 * K + goff, &sA[0][rbase][0]);
            if (ALO) gload_lds16(Alp + (size_t)m0 * K + goff, &sA[AP - 1][rbase][0]);
        }
        // W planes: TN rows = 4 waves x (TN/64) chunks x 16
#pragma unroll
        for (int c = 0; c < TN / 64; ++c) {
            int rbase = w * (TN / 4) + c * 16;
            int row = rbase + srow;
            int f = (row >> 1) & 3;
            size_t goff = (size_t)row * K + kk + (size_t)((sch ^ f)) * 8;
            gload_lds16(Whp + (size_t)n0 * K + goff, &sW[0][rbase][0]);
            if (WLO) gload_lds16(Wlp + (size_t)n0 * K + goff, &sW[WP - 1][rbase][0]);
        }
        __syncthreads();

        bf16x8 a0[4], a1[4], b0[NF], b1[NF];
#pragma unroll
        for (int m = 0; m < 4; ++m) {
            int row = wr + m * 16 + lr;
            int sl = lg ^ ((row >> 1) & 3);
            a0[m] = *(const bf16x8*)&sA[0][row][sl * 8];
            if (ALO) a1[m] = *(const bf16x8*)&sA[AP - 1][row][sl * 8];
        }
#pragma unroll
        for (int n = 0; n < NF; ++n) {
            int row = wc + n * 16 + lr;
            int sl = lg ^ ((row >> 1) & 3);
            b0[n] = *(const bf16x8*)&sW[0][row][sl * 8];
            if (WLO) b1[n] = *(const bf16x8*)&sW[WP - 1][row][sl * 8];
        }
        // hh pass, then (if WLO) hl, then (if ALO) lh
#pragma unroll
        for (int m = 0; m < 4; ++m)
#pragma unroll
            for (int n = 0; n < NF; ++n)
                acc[m][n] = __builtin_amdgcn_mfma_f32_16x16x32_bf16(a0[m], b0[n], acc[m][n], 0, 0, 0);
        if (WLO) {
#pragma unroll
            for (int m = 0; m < 4; ++m)
#pragma unroll
                for (int n = 0; n < NF; ++n)
                    acc[m][n] = __builtin_amdgcn_mfma_f32_16x16x32_bf16(a0[m], b1[n], acc[m][n], 0, 0, 0);
        }
        if (ALO) {
#pragma unroll
            for (int m = 0; m < 4; ++m)
#pragma unroll
                for (int n = 0; n < NF; ++n)
                    acc[m][n] = __builtin_amdgcn_mfma_f32_16x16x32_bf16(a1[m], b0[n], acc[m][n], 0, 0, 0);
        }
    }

#pragma unroll
    for (int m = 0; m < 4; ++m) {
#pragma unroll
        for (int n = 0; n < NF; ++n) {
            int col = n0 + wc + n * 16 + lr;
            float bv = bias[col];
#pragma unroll
            for (int r = 0; r < 4; ++r) {
                int row = m0 + wr + m * 16 + lg * 4 + r;
                float v = acc[m][n][r] + bv;
                if (RELU)  v = (v >= 0.0f) ? v : 0.1f * v;
                if (RESID) v += resid[(size_t)row * N + col];
                if (OUTM == 0) {
                    outf[(size_t)row * N + col] = v;
                } else if (OUTM == 2) {
                    outh[(size_t)row * N + col] = (bf16_t)v;
                } else {
                    bf16_t h = (bf16_t)v;
                    outh[(size_t)row * N + col] = h;
                    if (OUTM == 1 || col < 2048)
                        outl[(size_t)row * N + col] = (bf16_t)(v - (float)h);
                }
            }
        }
    }
}

// ---------------------------------------------------------------------------
// Flash attention from fused QKV planes (row stride 3D; q/k/v at col 0/D/2D).
// Block = 256 thr (4 waves), 128 q-rows per block (32/wave) -- r11 geometry
// restored (r12's 128-thr split regressed: same 8 waves/CU, more staging).
// XCD locality: h from blockIdx.x -> head's K/V pinned to one XCD L2
// (FETCH 106->20 MB, r11). Causal balance: qb from blockIdx.y, co-CU blocks
// complementary (r10). K(t+1) reg prefetch + single-barrier V dbuf (r9).
// QK^T split-precision (3 MFMA/pair); PV pure bf16-hi. O stored hi-only.
// ---------------------------------------------------------------------------
template<bool CAUSAL>
__global__ __launch_bounds__(256, 2) void attn_kernel(
    const bf16_t* __restrict__ qkvH, const bf16_t* __restrict__ qkvL,
    bf16_t* __restrict__ oh)
{
    __shared__ bf16_t Vth[2][64][70];  // double-buffered V^T (hi), pad 70
    __shared__ bf16_t Ph[4][32][70];   // per-wave P tile (hi)

    int tid = threadIdx.x;
    int b = blockIdx.z;
    int qb, h;
    if (CAUSAL) {
        int y = blockIdx.y;
        qb = (blockIdx.z & 2) ? (7 - (y & 7)) : (y & 7);
        h  = (blockIdx.x << 1) | (y >> 3);
    } else {
        h  = blockIdx.x;       // grid (NH, TT/128, BB): head pinned to XCD
        qb = blockIdx.y;
    }
    int l = tid & 63, w = tid >> 6;
    int lr = l & 15, lg = l >> 4;
    int qbase = qb * 128;
    const int QS = 3 * D;

    // Q frags: 32 rows per wave (2 x 16-row frags), hi/lo, both k-halves
    bf16x8 aqh[2][2], aql[2][2];
#pragma unroll
    for (int m = 0; m < 2; ++m) {
        size_t qoff = (size_t)(b * TT + qbase + w * 32 + m * 16 + lr) * QS + h * HS;
#pragma unroll
        for (int c = 0; c < 2; ++c) {
            aqh[m][c] = *(const bf16x8*)(qkvH + qoff + c * 32 + lg * 8);
            aql[m][c] = *(const bf16x8*)(qkvL + qoff + c * 32 + lg * 8);
        }
    }

    float mrow[2][4], lsum[2][4];
    f32x4 acc_o[2][4] = {};
#pragma unroll
    for (int m = 0; m < 2; ++m)
#pragma unroll
        for (int r = 0; r < 4; ++r) { mrow[m][r] = -1e30f; lsum[m][r] = 0.0f; }

    int ktmax = CAUSAL ? (2 * qb + 1) : (TT / 64 - 1);

    int vrow = tid >> 3;          // 0..31 (2 rows per thread, +32 apart)
    int vcol = (tid & 7) * 8;

    // prologue: V(0) -> LDS buf0; K(0) -> regs
    bf16x8 vreg[2];
#pragma unroll
    for (int rr = 0; rr < 2; ++rr)
        vreg[rr] = *(const bf16x8*)(qkvH + (size_t)(b * TT + vrow + rr * 32) * QS + 2 * D + h * HS + vcol);
#pragma unroll
    for (int rr = 0; rr < 2; ++rr)
#pragma unroll
        for (int j = 0; j < 8; ++j) Vth[0][vcol + j][vrow + rr * 32] = vreg[rr][j];

    bf16x8 kh0[4], kl0[4], kh1[4], kl1[4];
    {
        size_t koff = (size_t)(b * TT + lr) * QS + D + h * HS;
#pragma unroll
        for (int nt = 0; nt < 4; ++nt) {
            size_t ko = koff + (size_t)(nt * 16) * QS;
            kh0[nt] = *(const bf16x8*)(qkvH + ko + lg * 8);
            kl0[nt] = *(const bf16x8*)(qkvL + ko + lg * 8);
            kh1[nt] = *(const bf16x8*)(qkvH + ko + 32 + lg * 8);
            kl1[nt] = *(const bf16x8*)(qkvL + ko + 32 + lg * 8);
        }
    }
    __syncthreads();
    int cur = 0;

    for (int kt = 0; kt <= ktmax; ++kt) {
        int kbase = kt * 64;
        int ktn = kt < ktmax ? kt + 1 : ktmax;

        // issue V(t+1) loads (hide under QK^T + softmax + PV)
#pragma unroll
        for (int rr = 0; rr < 2; ++rr)
            vreg[rr] = *(const bf16x8*)(qkvH + (size_t)(b * TT + ktn * 64 + vrow + rr * 32) * QS + 2 * D + h * HS + vcol);

        // S = Q K^T  (32 q-rows x 64 k-cols per wave), split 3-MFMA, K from regs
        f32x4 accs[2][4];
#pragma unroll
        for (int nt = 0; nt < 4; ++nt) {
            __builtin_amdgcn_s_setprio(1);
#pragma unroll
            for (int m = 0; m < 2; ++m) {
                f32x4 s = {};
                s = __builtin_amdgcn_mfma_f32_16x16x32_bf16(aqh[m][0], kh0[nt], s, 0, 0, 0);
                s = __builtin_amdgcn_mfma_f32_16x16x32_bf16(aqh[m][0], kl0[nt], s, 0, 0, 0);
                s = __builtin_amdgcn_mfma_f32_16x16x32_bf16(aql[m][0], kh0[nt], s, 0, 0, 0);
                s = __builtin_amdgcn_mfma_f32_16x16x32_bf16(aqh[m][1], kh1[nt], s, 0, 0, 0);
                s = __builtin_amdgcn_mfma_f32_16x16x32_bf16(aqh[m][1], kl1[nt], s, 0, 0, 0);
                s = __builtin_amdgcn_mfma_f32_16x16x32_bf16(aql[m][1], kh1[nt], s, 0, 0, 0);
                accs[m][nt] = s * 8.0f;   // * sqrt(head_size), faithful to reference
            }
            __builtin_amdgcn_s_setprio(0);
        }

        // prefetch K(t+1) fragments (old K regs dead; softmax+PV hide latency)
        {
            size_t koffn = (size_t)(b * TT + ktn * 64 + lr) * QS + D + h * HS;
#pragma unroll
            for (int nt = 0; nt < 4; ++nt) {
                size_t ko = koffn + (size_t)(nt * 16) * QS;
                kh0[nt] = *(const bf16x8*)(qkvH + ko + lg * 8);
                kl0[nt] = *(const bf16x8*)(qkvL + ko + lg * 8);
                kh1[nt] = *(const bf16x8*)(qkvH + ko + 32 + lg * 8);
                kl1[nt] = *(const bf16x8*)(qkvL + ko + 32 + lg * 8);
            }
        }

        if (CAUSAL && kt >= 2 * qb) {
#pragma unroll
            for (int m = 0; m < 2; ++m)
#pragma unroll
                for (int nt = 0; nt < 4; ++nt)
#pragma unroll
                    for (int r = 0; r < 4; ++r) {
                        int qrow = qbase + w * 32 + m * 16 + lg * 4 + r;
                        int kcol = kbase + nt * 16 + lr;
                        if (kcol > qrow) accs[m][nt][r] = -1e30f;
                    }
        }

        // online softmax (row-wise over the 16 lanes holding this row)
#pragma unroll
        for (int m = 0; m < 2; ++m) {
            float alpha[4];
#pragma unroll
            for (int r = 0; r < 4; ++r) {
                float mx = fmaxf(fmaxf(accs[m][0][r], accs[m][1][r]),
                                 fmaxf(accs[m][2][r], accs[m][3][r]));
#pragma unroll
                for (int msk = 1; msk < 16; msk <<= 1) mx = fmaxf(mx, __shfl_xor(mx, msk, 64));
                float mnew = fmaxf(mrow[m][r], mx);
                float sum = 0.0f;
#pragma unroll
                for (int nt = 0; nt < 4; ++nt) {
                    float p = __expf(accs[m][nt][r] - mnew);
                    accs[m][nt][r] = p;
                    sum += p;
                }
#pragma unroll
                for (int msk = 1; msk < 16; msk <<= 1) sum += __shfl_xor(sum, msk, 64);
                alpha[r] = __expf(mrow[m][r] - mnew);
                lsum[m][r] = lsum[m][r] * alpha[r] + sum;
                mrow[m][r] = mnew;
            }
#pragma unroll
            for (int et = 0; et < 4; ++et)
#pragma unroll
                for (int r = 0; r < 4; ++r) acc_o[m][et][r] *= alpha[r];

            // P -> LDS (bf16 hi only; wave-private, no barrier needed)
#pragma unroll
            for (int nt = 0; nt < 4; ++nt)
#pragma unroll
                for (int r = 0; r < 4; ++r)
                    Ph[w][m * 16 + lg * 4 + r][nt * 16 + lr] = (bf16_t)accs[m][nt][r];
        }

        // O += P @ V  (pure bf16) from current V buffer
#pragma unroll
        for (int m = 0; m < 2; ++m) {
            bf16x8 ap0 = *(const bf16x8*)&Ph[w][m * 16 + lr][lg * 8];
            bf16x8 ap1 = *(const bf16x8*)&Ph[w][m * 16 + lr][32 + lg * 8];
            __builtin_amdgcn_s_setprio(1);
#pragma unroll
            for (int et = 0; et < 4; ++et) {
                bf16x8 bv0 = *(const bf16x8*)&Vth[cur][et * 16 + lr][lg * 8];
                bf16x8 bv1 = *(const bf16x8*)&Vth[cur][et * 16 + lr][32 + lg * 8];
                acc_o[m][et] = __builtin_amdgcn_mfma_f32_16x16x32_bf16(ap0, bv0, acc_o[m][et], 0, 0, 0);
                acc_o[m][et] = __builtin_amdgcn_mfma_f32_16x16x32_bf16(ap1, bv1, acc_o[m][et], 0, 0, 0);
            }
            __builtin_amdgcn_s_setprio(0);
        }

        // stage V(t+1) into the other buffer, then the single barrier
#pragma unroll
        for (int rr = 0; rr < 2; ++rr)
#pragma unroll
            for (int j = 0; j < 8; ++j) Vth[cur ^ 1][vcol + j][vrow + rr * 32] = vreg[rr][j];
        __syncthreads();
        cur ^= 1;
    }

#pragma unroll
    for (int m = 0; m < 2; ++m) {
        size_t obase = (size_t)(b * TT + qbase + w * 32 + m * 16) * D + h * HS;
#pragma unroll
        for (int r = 0; r < 4; ++r) {
            float inv = 1.0f / lsum[m][r];
#pragma unroll
            for (int et = 0; et < 4; ++et) {
                float v = acc_o[m][et][r] * inv;
                size_t idx = obase + (size_t)(lg * 4 + r) * D + et * 16 + lr;
                oh[idx] = (bf16_t)v;
            }
        }
    }
}

// ---------------------------------------------------------------------------
extern "C" void kernel_launch(void* const* d_in, const int* in_sizes, int n_in,
                              void* d_out, int out_size, void* d_ws, size_t ws_size,
                              hipStream_t stream)
{
    const float* x     = (const float*)d_in[0];
    const float* Wq    = (const float*)d_in[1];
    const float* bq    = (const float*)d_in[2];
    const float* Wk    = (const float*)d_in[3];
    const float* bk    = (const float*)d_in[4];
    const float* Wv    = (const float*)d_in[5];
    const float* bv    = (const float*)d_in[6];
    const float* Wp    = (const float*)d_in[7];
    const float* bp    = (const float*)d_in[8];
    const float* gamma = (const float*)d_in[9];
    const float* W1    = (const float*)d_in[10];
    const float* b1    = (const float*)d_in[11];
    const float* W2    = (const float*)d_in[12];
    const float* b2    = (const float*)d_in[13];
    float* out = (float*)d_out;

    // workspace layout (96 MB):
    //  0..16  : nrm hi/lo (8 MB each); ao hi (aliased)
    // 16..64  : qkv hi (24) + qkv lo (24); h1 bf16-hi (32) aliases 16..48
    // 48..64  : W1 conv slot (16 MB, ffn phase; aliases qkv lo tail)
    // 64..80  : bias3072 (attn phases) / W2 conv slot (8 MB used, ffn phase)
    // 80..96  : persistent attn weights: wqkv hi 6, wqkv lo 6, wp hi 2, wp lo 2
    char* base = (char*)d_ws;
    bf16_t* nrmH  = (bf16_t*)(base);
    bf16_t* nrmL  = (bf16_t*)(base + (8u  << 20));
    bf16_t* qkvH  = (bf16_t*)(base + (16u << 20));
    bf16_t* qkvL  = (bf16_t*)(base + (40u << 20));
    bf16_t* h1H   = (bf16_t*)(base + (16u << 20));   // 32 MB, hi only
    bf16_t* w1sl  = (bf16_t*)(base + (48u << 20));   // 16 MB (hi+lo)
    float*  bias3 = (float*)(base + (64u << 20));
    bf16_t* w2sl  = (bf16_t*)(base + (64u << 20));   // 8 MB (hi only)
    bf16_t* wsl   = (bf16_t*)(base + (80u << 20));   // 16 MB persistent
    bf16_t* aoH = nrmH;
    float* abuf = out;   // 'a' lives in d_out, dead before final write
    float* bbuf = out;   // 'b' overwrites 'a' in d_out (a unused after rmsnorm)

    // persistent attn weights: wqkv hi [3072][1024], wqkv lo, wp hi, wp lo
    size_t DD = (size_t)D * D;
    bf16_t* wqkvH = wsl;
    bf16_t* wqkvL = wsl + 3 * DD;
    bf16_t* wpH   = wsl + 6 * DD;
    bf16_t* wpL   = wsl + 7 * DD;

    dim3 blk(256);
    dim3 gcvD(D / 64, D / 64);
    dim3 gcv1(D / 64, HF / 64);
    dim3 gcv2(HF / 64, D / 64);
    dim3 gQKV(3 * D / 128, MR / 128);   // 24 x 32 = 768 blocks, TN=128
    dim3 gP(D / 64, MR / 128);          // 16 x 32 = 512 blocks, TN=64
    dim3 gF(HF / 128, MR / 128);        // 32 x 32 = 1024 blocks, TN=128
    dim3 gAnc(NH, TT / 128, BB);        // non-causal: head pinned to XCD
    dim3 gAc(TT / 128, NH, BB);         // causal: r10 balanced mapping

    // ---- a = x + attn(rmsnorm(x), causal=false)
    rmsnorm_kernel<true><<<MR, blk, 0, stream>>>(x, gamma, nrmH, nrmL);
    concat_bias_kernel<<<12, blk, 0, stream>>>(bq, bk, bv, bias3);
    convw_kernel<true><<<gcvD, blk, 0, stream>>>(Wq, wqkvH,          wqkvL,          D, D);
    convw_kernel<true><<<gcvD, blk, 0, stream>>>(Wk, wqkvH + DD,     wqkvL + DD,     D, D);
    convw_kernel<true><<<gcvD, blk, 0, stream>>>(Wv, wqkvH + 2 * DD, wqkvL + 2 * DD, D, D);
    convw_kernel<true><<<gcvD, blk, 0, stream>>>(Wp, wpH,            wpL,            D, D);
    gemm_kernel<128, false, true, true, 3, false, false><<<gQKV, blk, 0, stream>>>(nrmH, nrmL, wqkvH, wqkvL, bias3, nullptr, nullptr, qkvH, qkvL, 3 * D, D);
    attn_kernel<false><<<gAnc, blk, 0, stream>>>(qkvH, qkvL, aoH);
    gemm_kernel<64, false, false, true, 0, false, true><<<gP, blk, 0, stream>>>(aoH, nullptr, wpH, wpL, bp, x, abuf, nullptr, nullptr, D, D);

    // ---- b = x + ffwd(rmsnorm(a))
    rmsnorm_kernel<false><<<MR, blk, 0, stream>>>(abuf, gamma, nrmH, nullptr);
    convw_kernel<true><<<gcv1, blk, 0, stream>>>(W1, w1sl, w1sl + (size_t)HF * D, D, HF);
    gemm_kernel<128, true, false, true, 2, true, false><<<gF, blk, 0, stream>>>(nrmH, nullptr, w1sl, w1sl + (size_t)HF * D, b1, nullptr, nullptr, h1H, nullptr, HF, D);
    convw_kernel<false><<<gcv2, blk, 0, stream>>>(W2, w2sl, nullptr, HF, D);
    gemm_kernel<64, false, false, false, 0, false, true><<<gP, blk, 0, stream>>>(h1H, nullptr, w2sl, nullptr, b2, x, bbuf, nullptr, nullptr, D, HF);

    // ---- c = b + attn(rmsnorm(b), causal=true)  (attn weights still resident)
    rmsnorm_kernel<true><<<MR, blk, 0, stream>>>(bbuf, gamma, nrmH, nrmL);
    concat_bias_kernel<<<12, blk, 0, stream>>>(bq, bk, bv, bias3);
    gemm_kernel<128, false, true, true, 3, false, false><<<gQKV, blk, 0, stream>>>(nrmH, nrmL, wqkvH, wqkvL, bias3, nullptr, nullptr, qkvH, qkvL, 3 * D, D);
    attn_kernel<true><<<gAc, blk, 0, stream>>>(qkvH, qkvL, aoH);
    gemm_kernel<64, false, false, true, 0, false, true><<<gP, blk, 0, stream>>>(aoH, nullptr, wpH, wpL, bp, bbuf, out, nullptr, nullptr, D, D);
}